// Round 2
// baseline (4681.318 us; speedup 1.0000x reference)
//
#include <hip/hip_runtime.h>
#include <hip/hip_bf16.h>
#include <math.h>

// Problem constants: B=512, S=78, D=1024, H=16, DK=64
#define TB 512
#define TS 78
#define TD 1024
#define TH 16
#define TDK 64
#define TM (TB * TS)   // 39936 rows; 39936 % 128 == 0

typedef _Float16 f16x8 __attribute__((ext_vector_type(8)));
typedef float f32x4 __attribute__((ext_vector_type(4)));

typedef const __attribute__((address_space(1))) unsigned int* as1_u32p;
typedef __attribute__((address_space(3))) unsigned int* as3_u32p;

__device__ __forceinline__ void gload_lds16(const void* g, void* l) {
    // async global->LDS, 16B per lane; LDS dest = wave-uniform base + lane*16
    __builtin_amdgcn_global_load_lds((as1_u32p)g, (as3_u32p)l, 16, 0, 0);
}

// ---------------------------------------------------------------------------
// Split-precision fp16 MFMA GEMM:  C = A @ W^T  (fp32-equivalent accuracy)
//   A planes: Ah,Al [M,K] f16;  W planes: Wh,Wl [N,K] f16
//   acc += Ah*Wh + Ah*Wl + Al*Wh   (3x mfma_f32_16x16x32_f16)
// MODE 0: C row-major [M,N].  MODE 1: C as [B,H,S,DK].
// m97 structure: 128x128 tile, BK=32, 4 waves (2x2), global_load_lds w=16.
// ---------------------------------------------------------------------------
template<int MODE>
__global__ __launch_bounds__(256)
void gemm_split(const _Float16* __restrict__ Ah, const _Float16* __restrict__ Al,
                const _Float16* __restrict__ Wh, const _Float16* __restrict__ Wl,
                float* __restrict__ C)
{
    constexpr int K = 1024, N = 1024, BM = 128, BN = 128, BK = 32;
    __shared__ _Float16 sA[2][BM * BK];   // [hi/lo][row*32+k], 64B rows
    __shared__ _Float16 sB[2][BN * BK];

    const int tid  = threadIdx.x;
    const int lane = tid & 63;
    const int wave = tid >> 6;

    // XCD-aware bijective swizzle (nwg = 2496, nwg % 8 == 0)
    const int nwg = gridDim.x;
    const int wg  = (blockIdx.x & 7) * (nwg >> 3) + (blockIdx.x >> 3);
    const int bm0 = (wg >> 3) << 7;   // 312 row panels
    const int bn0 = (wg & 7) << 7;    // 8 col panels

    // staging: 512 16B-chunks per array = 8 wave-issues; thread does 2/array
    const int c0 = (wave + 0) * 64 + lane;
    const int c1 = (wave + 4) * 64 + lane;
    const int r0 = c0 >> 2, k00 = (c0 & 3) << 3;
    const int r1 = c1 >> 2, k01 = (c1 & 3) << 3;
    const int d0 = (wave + 0) * 512;   // LDS elem offset (wave-uniform)
    const int d1 = (wave + 4) * 512;

    const _Float16* gA0h = Ah + (size_t)(bm0 + r0) * K + k00;
    const _Float16* gA1h = Ah + (size_t)(bm0 + r1) * K + k01;
    const _Float16* gA0l = Al + (size_t)(bm0 + r0) * K + k00;
    const _Float16* gA1l = Al + (size_t)(bm0 + r1) * K + k01;
    const _Float16* gB0h = Wh + (size_t)(bn0 + r0) * K + k00;
    const _Float16* gB1h = Wh + (size_t)(bn0 + r1) * K + k01;
    const _Float16* gB0l = Wl + (size_t)(bn0 + r0) * K + k00;
    const _Float16* gB1l = Wl + (size_t)(bn0 + r1) * K + k01;

    const int wm = wave >> 1, wn = wave & 1;   // 2x2 wave grid, 64x64/wave
    const int fr = lane & 15;
    const int fk = (lane >> 4) << 3;           // 8 contiguous k per lane

    f32x4 acc[4][4] = {};

    for (int kt = 0; kt < K; kt += BK) {
        gload_lds16(gA0h + kt, &sA[0][d0]);
        gload_lds16(gA1h + kt, &sA[0][d1]);
        gload_lds16(gA0l + kt, &sA[1][d0]);
        gload_lds16(gA1l + kt, &sA[1][d1]);
        gload_lds16(gB0h + kt, &sB[0][d0]);
        gload_lds16(gB1h + kt, &sB[0][d1]);
        gload_lds16(gB0l + kt, &sB[1][d0]);
        gload_lds16(gB1l + kt, &sB[1][d1]);
        __syncthreads();   // drains vmcnt: staged tile visible

        f16x8 ah[4], al[4], bh[4], bl[4];
#pragma unroll
        for (int mi = 0; mi < 4; ++mi) {
            const int row = wm * 64 + mi * 16 + fr;
            ah[mi] = *(const f16x8*)&sA[0][row * BK + fk];
            al[mi] = *(const f16x8*)&sA[1][row * BK + fk];
        }
#pragma unroll
        for (int nj = 0; nj < 4; ++nj) {
            const int row = wn * 64 + nj * 16 + fr;
            bh[nj] = *(const f16x8*)&sB[0][row * BK + fk];
            bl[nj] = *(const f16x8*)&sB[1][row * BK + fk];
        }
#pragma unroll
        for (int mi = 0; mi < 4; ++mi)
#pragma unroll
            for (int nj = 0; nj < 4; ++nj) {
                acc[mi][nj] = __builtin_amdgcn_mfma_f32_16x16x32_f16(ah[mi], bh[nj], acc[mi][nj], 0, 0, 0);
                acc[mi][nj] = __builtin_amdgcn_mfma_f32_16x16x32_f16(ah[mi], bl[nj], acc[mi][nj], 0, 0, 0);
                acc[mi][nj] = __builtin_amdgcn_mfma_f32_16x16x32_f16(al[mi], bh[nj], acc[mi][nj], 0, 0, 0);
            }
        __syncthreads();   // done reading before next tile overwrites
    }

    // C/D layout: col = lane&15, row = (lane>>4)*4 + reg  [m89-verified]
#pragma unroll
    for (int mi = 0; mi < 4; ++mi)
#pragma unroll
        for (int nj = 0; nj < 4; ++nj) {
            const int rowb = bm0 + wm * 64 + mi * 16 + ((lane >> 4) << 2);
            const int col  = bn0 + wn * 64 + nj * 16 + fr;
#pragma unroll
            for (int q = 0; q < 4; ++q) {
                const int r = rowb + q;
                if (MODE == 0) {
                    C[(size_t)r * N + col] = acc[mi][nj][q];
                } else {
                    const int b = r / TS, s = r - b * TS;
                    const int h = col >> 6, dk = col & 63;
                    C[(((size_t)b * TH + h) * TS + s) * TDK + dk] = acc[mi][nj][q];
                }
            }
        }
}

// ---------------------------------------------------------------------------
// fp32 -> (hi,lo) fp16 plane split, 8 elems/thread, grid-stride
// ---------------------------------------------------------------------------
__global__ __launch_bounds__(256)
void cvt_split(const float* __restrict__ x, _Float16* __restrict__ hi,
               _Float16* __restrict__ lo, int n8)
{
    for (int i = blockIdx.x * 256 + threadIdx.x; i < n8; i += gridDim.x * 256) {
        const float4* xp = (const float4*)x + (size_t)i * 2;
        const float4 a = xp[0], b = xp[1];
        const float v[8] = {a.x, a.y, a.z, a.w, b.x, b.y, b.z, b.w};
        f16x8 h, l;
#pragma unroll
        for (int j = 0; j < 8; ++j) {
            const _Float16 hv = (_Float16)v[j];
            h[j] = hv;
            l[j] = (_Float16)(v[j] - (float)hv);
        }
        *((f16x8*)hi + i) = h;
        *((f16x8*)lo + i) = l;
    }
}

// ---------------------------------------------------------------------------
// fp32 vector-ALU GEMM (fallback path when ws is too small for split planes)
// ---------------------------------------------------------------------------
template<int MODE>
__global__ __launch_bounds__(256)
void gemm_nt_kernel(const float* __restrict__ A, const float* __restrict__ W,
                    float* __restrict__ C)
{
    constexpr int BM = 128, BN = 128, BK = 16, K = 1024, N = 1024;
    __shared__ float As[BK][BM];
    __shared__ float Bs[BK][BN];

    const int tid = threadIdx.x;
    const int bm0 = blockIdx.y * BM;
    const int bn0 = blockIdx.x * BN;
    const int tx = tid & 15;
    const int ty = tid >> 4;
    const int lrow = tid >> 1;
    const int lk   = (tid & 1) * 8;

    const float* Ap = A + (size_t)(bm0 + lrow) * K + lk;
    const float* Wp = W + (size_t)(bn0 + lrow) * K + lk;

    float acc[8][8];
#pragma unroll
    for (int i = 0; i < 8; ++i)
#pragma unroll
        for (int j = 0; j < 8; ++j) acc[i][j] = 0.f;

    float4 ra0 = *(const float4*)(Ap + 0);
    float4 ra1 = *(const float4*)(Ap + 4);
    float4 rw0 = *(const float4*)(Wp + 0);
    float4 rw1 = *(const float4*)(Wp + 4);

    for (int kt = 0; kt < K; kt += BK) {
        __syncthreads();
        As[lk+0][lrow]=ra0.x; As[lk+1][lrow]=ra0.y; As[lk+2][lrow]=ra0.z; As[lk+3][lrow]=ra0.w;
        As[lk+4][lrow]=ra1.x; As[lk+5][lrow]=ra1.y; As[lk+6][lrow]=ra1.z; As[lk+7][lrow]=ra1.w;
        Bs[lk+0][lrow]=rw0.x; Bs[lk+1][lrow]=rw0.y; Bs[lk+2][lrow]=rw0.z; Bs[lk+3][lrow]=rw0.w;
        Bs[lk+4][lrow]=rw1.x; Bs[lk+5][lrow]=rw1.y; Bs[lk+6][lrow]=rw1.z; Bs[lk+7][lrow]=rw1.w;
        __syncthreads();
        const int kn = kt + BK;
        if (kn < K) {
            ra0 = *(const float4*)(Ap + kn);
            ra1 = *(const float4*)(Ap + kn + 4);
            rw0 = *(const float4*)(Wp + kn);
            rw1 = *(const float4*)(Wp + kn + 4);
        }
#pragma unroll
        for (int k = 0; k < BK; ++k) {
            float a[8], b[8];
            *(float4*)&a[0] = *(const float4*)&As[k][ty * 8];
            *(float4*)&a[4] = *(const float4*)&As[k][ty * 8 + 4];
            *(float4*)&b[0] = *(const float4*)&Bs[k][tx * 8];
            *(float4*)&b[4] = *(const float4*)&Bs[k][tx * 8 + 4];
#pragma unroll
            for (int i = 0; i < 8; ++i)
#pragma unroll
                for (int j = 0; j < 8; ++j)
                    acc[i][j] = fmaf(a[i], b[j], acc[i][j]);
        }
    }

    if (MODE == 0) {
#pragma unroll
        for (int i = 0; i < 8; ++i) {
            const int row = bm0 + ty * 8 + i;
            float* cp = C + (size_t)row * N + bn0 + tx * 8;
            float4 c0 = {acc[i][0], acc[i][1], acc[i][2], acc[i][3]};
            float4 c1 = {acc[i][4], acc[i][5], acc[i][6], acc[i][7]};
            *(float4*)(cp + 0) = c0;
            *(float4*)(cp + 4) = c1;
        }
    } else {
        const int o0 = bn0 + tx * 8;
        const int h  = o0 >> 6;
        const int dk = o0 & 63;
#pragma unroll
        for (int i = 0; i < 8; ++i) {
            const int n = bm0 + ty * 8 + i;
            const int b = n / TS;
            const int s = n - b * TS;
            float* cp = C + (((size_t)b * TH + h) * TS + s) * TDK + dk;
            float4 c0 = {acc[i][0], acc[i][1], acc[i][2], acc[i][3]};
            float4 c1 = {acc[i][4], acc[i][5], acc[i][6], acc[i][7]};
            *(float4*)(cp + 0) = c0;
            *(float4*)(cp + 4) = c1;
        }
    }
}

// ---------------------------------------------------------------------------
// Fused attention: one block per (b,h). fp32 vector path.
// ---------------------------------------------------------------------------
__global__ __launch_bounds__(256)
void attn_kernel(const float* __restrict__ Q, const float* __restrict__ Kin,
                 const float* __restrict__ V, const float* __restrict__ bias,
                 float* __restrict__ ctx)
{
    constexpr int S = TS, DK = TDK, SP = 80;
    __shared__ float Qs[DK * SP];   // [dk][s]; reused as V [s][dk]
    __shared__ float Ks[DK * SP];   // [dk][s]
    __shared__ float Ss[SP * SP];   // scores k-major: [k][q]

    const int tid = threadIdx.x;
    const int bh = blockIdx.x;
    const int b  = bh >> 4;
    const int h  = bh & 15;
    const float* qg = Q   + (size_t)bh * S * DK;
    const float* kg = Kin + (size_t)bh * S * DK;
    const float* vg = V   + (size_t)bh * S * DK;
    const float* bi = bias + (size_t)h * S * S;

    for (int i = tid; i < DK * SP; i += 256) {
        const int dk = i / SP;
        const int s  = i - dk * SP;
        float qv = 0.f, kv = 0.f;
        if (s < S) { qv = qg[s * DK + dk]; kv = kg[s * DK + dk]; }
        Qs[i] = qv; Ks[i] = kv;
    }
    __syncthreads();

    for (int t = tid; t < 400; t += 256) {
        const int tr = (t / 20) * 4;
        const int tc = (t % 20) * 4;
        float acc[4][4];
#pragma unroll
        for (int i = 0; i < 4; ++i)
#pragma unroll
            for (int j = 0; j < 4; ++j) acc[i][j] = 0.f;
        for (int kk = 0; kk < DK; ++kk) {
            const float4 a = *(const float4*)&Qs[kk * SP + tr];
            const float4 c = *(const float4*)&Ks[kk * SP + tc];
            const float av[4] = {a.x, a.y, a.z, a.w};
            const float cv[4] = {c.x, c.y, c.z, c.w};
#pragma unroll
            for (int i = 0; i < 4; ++i)
#pragma unroll
                for (int j = 0; j < 4; ++j)
                    acc[i][j] = fmaf(av[i], cv[j], acc[i][j]);
        }
#pragma unroll
        for (int j = 0; j < 4; ++j) {
            const int c = tc + j;
            float4 o;
            o.x = acc[0][j] * 0.125f + ((tr + 0 < S && c < S) ? bi[(tr + 0) * S + c] : 0.f);
            o.y = acc[1][j] * 0.125f + ((tr + 1 < S && c < S) ? bi[(tr + 1) * S + c] : 0.f);
            o.z = acc[2][j] * 0.125f + ((tr + 2 < S && c < S) ? bi[(tr + 2) * S + c] : 0.f);
            o.w = acc[3][j] * 0.125f + ((tr + 3 < S && c < S) ? bi[(tr + 3) * S + c] : 0.f);
            *(float4*)&Ss[c * SP + tr] = o;
        }
    }
    __syncthreads();

    for (int i = tid; i < S * DK; i += 256) Qs[i] = vg[i];
    if (tid < S) {
        const int r = tid;
        float m = -1e30f;
        for (int c = 0; c < S; ++c) m = fmaxf(m, Ss[c * SP + r]);
        float sum = 0.f;
        for (int c = 0; c < S; ++c) {
            const float e = __expf(Ss[c * SP + r] - m);
            Ss[c * SP + r] = e;
            sum += e;
        }
        const float inv = 1.f / sum;
        for (int c = 0; c < S; ++c) Ss[c * SP + r] *= inv;
    }
    __syncthreads();

    for (int t = tid; t < 320; t += 256) {
        const int tr = (t >> 4) * 4;
        const int tc = (t & 15) * 4;
        float acc[4][4];
#pragma unroll
        for (int i = 0; i < 4; ++i)
#pragma unroll
            for (int j = 0; j < 4; ++j) acc[i][j] = 0.f;
        for (int c = 0; c < S; ++c) {
            const float4 p = *(const float4*)&Ss[c * SP + tr];
            const float4 vv = *(const float4*)&Qs[c * DK + tc];
            const float pv[4] = {p.x, p.y, p.z, p.w};
            const float vj[4] = {vv.x, vv.y, vv.z, vv.w};
#pragma unroll
            for (int i = 0; i < 4; ++i)
#pragma unroll
                for (int j = 0; j < 4; ++j)
                    acc[i][j] = fmaf(pv[i], vj[j], acc[i][j]);
        }
#pragma unroll
        for (int i = 0; i < 4; ++i) {
            const int r = tr + i;
            if (r < S) {
                float4 o = {acc[i][0], acc[i][1], acc[i][2], acc[i][3]};
                *(float4*)&ctx[((size_t)(b * S + r) * TD) + h * DK + tc] = o;
            }
        }
    }
}

// ---------------------------------------------------------------------------
extern "C" void kernel_launch(void* const* d_in, const int* in_sizes, int n_in,
                              void* d_out, int out_size, void* d_ws, size_t ws_size,
                              hipStream_t stream)
{
    const float* query = (const float*)d_in[0];
    const float* key   = (const float*)d_in[1];
    const float* value = (const float*)d_in[2];
    // d_in[3] = token_coords (int64) — unused by the reference
    const float* Wq = (const float*)d_in[4];
    const float* Wk = (const float*)d_in[5];
    const float* Wv = (const float*)d_in[6];
    const float* Wo = (const float*)d_in[7];
    const float* rb = (const float*)d_in[8];
    float* out = (float*)d_out;

    const size_t U  = (size_t)TM * TD;         // 40,894,464 elems
    const size_t UW = (size_t)TD * TD;         // 1,048,576 elems
    const size_t SPLIT_BYTES = 5 * U * 4 + 8 * UW * 2;   // ~835 MB

    char* ws = (char*)d_ws;

    if (ws_size >= SPLIT_BYTES) {
        // ------- split-precision MFMA path -------
        // region map (each region U floats = 4U bytes):
        //  A: qw | B: kw | C: qh/ql -> vw | D: kh/kl -> cw | E: vh/vl -> ch/cl | F: W planes
        float*    qw = (float*)ws;
        float*    kw = (float*)(ws + 1 * U * 4);
        _Float16* qh = (_Float16*)(ws + 2 * U * 4);
        _Float16* ql = qh + U;
        float*    vw = (float*)(ws + 2 * U * 4);      // reuse C after GEMM-Q
        _Float16* kh = (_Float16*)(ws + 3 * U * 4);
        _Float16* kl = kh + U;
        float*    cw = (float*)(ws + 3 * U * 4);      // reuse D after GEMM-K
        _Float16* vh = (_Float16*)(ws + 4 * U * 4);
        _Float16* vl = vh + U;
        _Float16* ch = (_Float16*)(ws + 4 * U * 4);   // reuse E after GEMM-V
        _Float16* cl = ch + U;
        _Float16* wp = (_Float16*)(ws + 5 * U * 4);   // 8 planes of UW halves
        _Float16 *wqh = wp,          *wql = wp + UW;
        _Float16 *wkh = wp + 2 * UW, *wkl = wp + 3 * UW;
        _Float16 *wvh = wp + 4 * UW, *wvl = wp + 5 * UW;
        _Float16 *woh = wp + 6 * UW, *wol = wp + 7 * UW;

        const int n8a = (int)(U / 8);    // 5,111,808
        const int n8w = (int)(UW / 8);   // 131,072

        cvt_split<<<2048, 256, 0, stream>>>(query, qh, ql, n8a);
        cvt_split<<<2048, 256, 0, stream>>>(key,   kh, kl, n8a);
        cvt_split<<<2048, 256, 0, stream>>>(value, vh, vl, n8a);
        cvt_split<<<512, 256, 0, stream>>>(Wq, wqh, wql, n8w);
        cvt_split<<<512, 256, 0, stream>>>(Wk, wkh, wkl, n8w);
        cvt_split<<<512, 256, 0, stream>>>(Wv, wvh, wvl, n8w);
        cvt_split<<<512, 256, 0, stream>>>(Wo, woh, wol, n8w);

        const int nwg = (TM / 128) * (TD / 128);   // 2496
        gemm_split<1><<<nwg, 256, 0, stream>>>(qh, ql, wqh, wql, qw);
        gemm_split<1><<<nwg, 256, 0, stream>>>(kh, kl, wkh, wkl, kw);
        gemm_split<1><<<nwg, 256, 0, stream>>>(vh, vl, wvh, wvl, vw);
        attn_kernel<<<TB * TH, 256, 0, stream>>>(qw, kw, vw, rb, cw);
        cvt_split<<<2048, 256, 0, stream>>>(cw, ch, cl, n8a);
        gemm_split<0><<<nwg, 256, 0, stream>>>(ch, cl, woh, wol, out);
    } else {
        // ------- fp32 vector fallback -------
        float* qw = (float*)ws;
        float* kw = qw + U;
        float* vw = kw + U;
        float* cw = vw + U;
        dim3 grid(TD / 128, TM / 128);
        gemm_nt_kernel<1><<<grid, 256, 0, stream>>>(query, Wq, qw);
        gemm_nt_kernel<1><<<grid, 256, 0, stream>>>(key,   Wk, kw);
        gemm_nt_kernel<1><<<grid, 256, 0, stream>>>(value, Wv, vw);
        attn_kernel<<<TB * TH, 256, 0, stream>>>(qw, kw, vw, rb, cw);
        gemm_nt_kernel<0><<<grid, 256, 0, stream>>>(cw, Wo, out);
    }
}

// Round 12
// 2056.284 us; speedup vs baseline: 2.2766x; 2.2766x over previous
//
#include <hip/hip_runtime.h>
#include <hip/hip_bf16.h>
#include <math.h>

// Problem constants: B=512, S=78, D=1024, H=16, DK=64
#define TB 512
#define TS 78
#define TD 1024
#define TH 16
#define TDK 64
#define TM (TB * TS)   // 39936 rows; 39936 % 128 == 0

typedef _Float16 f16x8 __attribute__((ext_vector_type(8)));
typedef float f32x4 __attribute__((ext_vector_type(4)));

typedef const __attribute__((address_space(1))) unsigned int* as1_u32p;
typedef __attribute__((address_space(3))) unsigned int* as3_u32p;

__device__ __forceinline__ void gload_lds16(const void* g, void* l) {
    // async global->LDS, 16B per lane; LDS dest = wave-uniform base + lane*16
    __builtin_amdgcn_global_load_lds((as1_u32p)g, (as3_u32p)l, 16, 0, 0);
}

// ---------------------------------------------------------------------------
// Split-precision fp16 MFMA GEMM:  C = A @ W^T  (fp32-equivalent accuracy)
//   A planes: Ah,Al [M,K] f16;  W planes: Wh,Wl [N,K] f16
//   acc += Ah*Wh + Ah*Wl + Al*Wh   (3x mfma_f32_16x16x32_f16)
// MODE 0: C row-major [M,N].  MODE 1: C as [B,H,S,DK].
// m97 structure: 128x128 tile, BK=32, 4 waves (2x2), global_load_lds w=16.
// ---------------------------------------------------------------------------
template<int MODE>
__global__ __launch_bounds__(256)
void gemm_split(const _Float16* __restrict__ Ah, const _Float16* __restrict__ Al,
                const _Float16* __restrict__ Wh, const _Float16* __restrict__ Wl,
                float* __restrict__ C)
{
    constexpr int K = 1024, N = 1024, BM = 128, BK = 32;
    __shared__ _Float16 sA[2][BM * BK];   // [hi/lo][row*32+k], 64B rows
    __shared__ _Float16 sB[2][BM * BK];

    const int tid  = threadIdx.x;
    const int lane = tid & 63;
    const int wave = tid >> 6;

    // XCD-aware bijective swizzle (nwg = 2496, nwg % 8 == 0)
    const int nwg = gridDim.x;
    const int wg  = (blockIdx.x & 7) * (nwg >> 3) + (blockIdx.x >> 3);
    const int bm0 = (wg >> 3) << 7;   // 312 row panels
    const int bn0 = (wg & 7) << 7;    // 8 col panels

    // staging: 512 16B-chunks per array = 8 wave-issues; thread does 2/array
    const int c0 = (wave + 0) * 64 + lane;
    const int c1 = (wave + 4) * 64 + lane;
    const int r0 = c0 >> 2, k00 = (c0 & 3) << 3;
    const int r1 = c1 >> 2, k01 = (c1 & 3) << 3;
    const int d0 = (wave + 0) * 512;   // LDS elem offset (wave-uniform)
    const int d1 = (wave + 4) * 512;

    const _Float16* gA0h = Ah + (size_t)(bm0 + r0) * K + k00;
    const _Float16* gA1h = Ah + (size_t)(bm0 + r1) * K + k01;
    const _Float16* gA0l = Al + (size_t)(bm0 + r0) * K + k00;
    const _Float16* gA1l = Al + (size_t)(bm0 + r1) * K + k01;
    const _Float16* gB0h = Wh + (size_t)(bn0 + r0) * K + k00;
    const _Float16* gB1h = Wh + (size_t)(bn0 + r1) * K + k01;
    const _Float16* gB0l = Wl + (size_t)(bn0 + r0) * K + k00;
    const _Float16* gB1l = Wl + (size_t)(bn0 + r1) * K + k01;

    const int wm = wave >> 1, wn = wave & 1;   // 2x2 wave grid, 64x64/wave
    const int fr = lane & 15;
    const int fk = (lane >> 4) << 3;           // 8 contiguous k per lane

    f32x4 acc[4][4] = {};

    for (int kt = 0; kt < K; kt += BK) {
        gload_lds16(gA0h + kt, &sA[0][d0]);
        gload_lds16(gA1h + kt, &sA[0][d1]);
        gload_lds16(gA0l + kt, &sA[1][d0]);
        gload_lds16(gA1l + kt, &sA[1][d1]);
        gload_lds16(gB0h + kt, &sB[0][d0]);
        gload_lds16(gB1h + kt, &sB[0][d1]);
        gload_lds16(gB0l + kt, &sB[1][d0]);
        gload_lds16(gB1l + kt, &sB[1][d1]);
        __syncthreads();   // drains vmcnt: staged tile visible

        f16x8 ah[4], al[4], bh[4], bl[4];
#pragma unroll
        for (int mi = 0; mi < 4; ++mi) {
            const int row = wm * 64 + mi * 16 + fr;
            ah[mi] = *(const f16x8*)&sA[0][row * BK + fk];
            al[mi] = *(const f16x8*)&sA[1][row * BK + fk];
        }
#pragma unroll
        for (int nj = 0; nj < 4; ++nj) {
            const int row = wn * 64 + nj * 16 + fr;
            bh[nj] = *(const f16x8*)&sB[0][row * BK + fk];
            bl[nj] = *(const f16x8*)&sB[1][row * BK + fk];
        }
#pragma unroll
        for (int mi = 0; mi < 4; ++mi)
#pragma unroll
            for (int nj = 0; nj < 4; ++nj) {
                acc[mi][nj] = __builtin_amdgcn_mfma_f32_16x16x32_f16(ah[mi], bh[nj], acc[mi][nj], 0, 0, 0);
                acc[mi][nj] = __builtin_amdgcn_mfma_f32_16x16x32_f16(ah[mi], bl[nj], acc[mi][nj], 0, 0, 0);
                acc[mi][nj] = __builtin_amdgcn_mfma_f32_16x16x32_f16(al[mi], bh[nj], acc[mi][nj], 0, 0, 0);
            }
        __syncthreads();   // done reading before next tile overwrites
    }

    // C/D layout: col = lane&15, row = (lane>>4)*4 + reg  [m89-verified]
#pragma unroll
    for (int mi = 0; mi < 4; ++mi)
#pragma unroll
        for (int nj = 0; nj < 4; ++nj) {
            const int rowb = bm0 + wm * 64 + mi * 16 + ((lane >> 4) << 2);
            const int col  = bn0 + wn * 64 + nj * 16 + fr;
#pragma unroll
            for (int q = 0; q < 4; ++q) {
                const int r = rowb + q;
                if (MODE == 0) {
                    C[(size_t)r * N + col] = acc[mi][nj][q];
                } else {
                    const int b = r / TS, s = r - b * TS;
                    const int h = col >> 6, dk = col & 63;
                    C[(((size_t)b * TH + h) * TS + s) * TDK + dk] = acc[mi][nj][q];
                }
            }
        }
}

// ---------------------------------------------------------------------------
// fp32 -> (hi,lo) fp16 plane split, 8 elems/thread, grid-stride
// ---------------------------------------------------------------------------
__global__ __launch_bounds__(256)
void cvt_split(const float* __restrict__ x, _Float16* __restrict__ hi,
               _Float16* __restrict__ lo, int n8)
{
    for (int i = blockIdx.x * 256 + threadIdx.x; i < n8; i += gridDim.x * 256) {
        const float4* xp = (const float4*)x + (size_t)i * 2;
        const float4 a = xp[0], b = xp[1];
        const float v[8] = {a.x, a.y, a.z, a.w, b.x, b.y, b.z, b.w};
        f16x8 h, l;
#pragma unroll
        for (int j = 0; j < 8; ++j) {
            const _Float16 hv = (_Float16)v[j];
            h[j] = hv;
            l[j] = (_Float16)(v[j] - (float)hv);
        }
        *((f16x8*)hi + i) = h;
        *((f16x8*)lo + i) = l;
    }
}

// ---------------------------------------------------------------------------
// fp32 vector-ALU GEMM (fallback path only; not expected to run)
// ---------------------------------------------------------------------------
template<int MODE>
__global__ __launch_bounds__(256)
void gemm_nt_kernel(const float* __restrict__ A, const float* __restrict__ W,
                    float* __restrict__ C)
{
    constexpr int BM = 128, BN = 128, BK = 16, K = 1024, N = 1024;
    __shared__ float As[BK][BM];
    __shared__ float Bs[BK][BN];

    const int tid = threadIdx.x;
    const int bm0 = blockIdx.y * BM;
    const int bn0 = blockIdx.x * BN;
    const int tx = tid & 15;
    const int ty = tid >> 4;
    const int lrow = tid >> 1;
    const int lk   = (tid & 1) * 8;

    const float* Ap = A + (size_t)(bm0 + lrow) * K + lk;
    const float* Wp = W + (size_t)(bn0 + lrow) * K + lk;

    float acc[8][8];
#pragma unroll
    for (int i = 0; i < 8; ++i)
#pragma unroll
        for (int j = 0; j < 8; ++j) acc[i][j] = 0.f;

    float4 ra0 = *(const float4*)(Ap + 0);
    float4 ra1 = *(const float4*)(Ap + 4);
    float4 rw0 = *(const float4*)(Wp + 0);
    float4 rw1 = *(const float4*)(Wp + 4);

    for (int kt = 0; kt < K; kt += BK) {
        __syncthreads();
        As[lk+0][lrow]=ra0.x; As[lk+1][lrow]=ra0.y; As[lk+2][lrow]=ra0.z; As[lk+3][lrow]=ra0.w;
        As[lk+4][lrow]=ra1.x; As[lk+5][lrow]=ra1.y; As[lk+6][lrow]=ra1.z; As[lk+7][lrow]=ra1.w;
        Bs[lk+0][lrow]=rw0.x; Bs[lk+1][lrow]=rw0.y; Bs[lk+2][lrow]=rw0.z; Bs[lk+3][lrow]=rw0.w;
        Bs[lk+4][lrow]=rw1.x; Bs[lk+5][lrow]=rw1.y; Bs[lk+6][lrow]=rw1.z; Bs[lk+7][lrow]=rw1.w;
        __syncthreads();
        const int kn = kt + BK;
        if (kn < K) {
            ra0 = *(const float4*)(Ap + kn);
            ra1 = *(const float4*)(Ap + kn + 4);
            rw0 = *(const float4*)(Wp + kn);
            rw1 = *(const float4*)(Wp + kn + 4);
        }
#pragma unroll
        for (int k = 0; k < BK; ++k) {
            float a[8], b[8];
            *(float4*)&a[0] = *(const float4*)&As[k][ty * 8];
            *(float4*)&a[4] = *(const float4*)&As[k][ty * 8 + 4];
            *(float4*)&b[0] = *(const float4*)&Bs[k][tx * 8];
            *(float4*)&b[4] = *(const float4*)&Bs[k][tx * 8 + 4];
#pragma unroll
            for (int i = 0; i < 8; ++i)
#pragma unroll
                for (int j = 0; j < 8; ++j)
                    acc[i][j] = fmaf(a[i], b[j], acc[i][j]);
        }
    }

    if (MODE == 0) {
#pragma unroll
        for (int i = 0; i < 8; ++i) {
            const int row = bm0 + ty * 8 + i;
            float* cp = C + (size_t)row * N + bn0 + tx * 8;
            float4 c0 = {acc[i][0], acc[i][1], acc[i][2], acc[i][3]};
            float4 c1 = {acc[i][4], acc[i][5], acc[i][6], acc[i][7]};
            *(float4*)(cp + 0) = c0;
            *(float4*)(cp + 4) = c1;
        }
    } else {
        const int o0 = bn0 + tx * 8;
        const int h  = o0 >> 6;
        const int dk = o0 & 63;
#pragma unroll
        for (int i = 0; i < 8; ++i) {
            const int n = bm0 + ty * 8 + i;
            const int b = n / TS;
            const int s = n - b * TS;
            float* cp = C + (((size_t)b * TH + h) * TS + s) * TDK + dk;
            float4 c0 = {acc[i][0], acc[i][1], acc[i][2], acc[i][3]};
            float4 c1 = {acc[i][4], acc[i][5], acc[i][6], acc[i][7]};
            *(float4*)(cp + 0) = c0;
            *(float4*)(cp + 4) = c1;
        }
    }
}

// ---------------------------------------------------------------------------
// Fused attention: one block per (b,h). fp32 vector path (validated r2).
// ---------------------------------------------------------------------------
__global__ __launch_bounds__(256)
void attn_kernel(const float* __restrict__ Q, const float* __restrict__ Kin,
                 const float* __restrict__ V, const float* __restrict__ bias,
                 float* __restrict__ ctx)
{
    constexpr int S = TS, DK = TDK, SP = 80;
    __shared__ float Qs[DK * SP];   // [dk][s]; reused as V [s][dk]
    __shared__ float Ks[DK * SP];   // [dk][s]
    __shared__ float Ss[SP * SP];   // scores k-major: [k][q]

    const int tid = threadIdx.x;
    const int bh = blockIdx.x;
    const int b  = bh >> 4;
    const int h  = bh & 15;
    const float* qg = Q   + (size_t)bh * S * DK;
    const float* kg = Kin + (size_t)bh * S * DK;
    const float* vg = V   + (size_t)bh * S * DK;
    const float* bi = bias + (size_t)h * S * S;

    for (int i = tid; i < DK * SP; i += 256) {
        const int dk = i / SP;
        const int s  = i - dk * SP;
        float qv = 0.f, kv = 0.f;
        if (s < S) { qv = qg[s * DK + dk]; kv = kg[s * DK + dk]; }
        Qs[i] = qv; Ks[i] = kv;
    }
    __syncthreads();

    for (int t = tid; t < 400; t += 256) {
        const int tr = (t / 20) * 4;
        const int tc = (t % 20) * 4;
        float acc[4][4];
#pragma unroll
        for (int i = 0; i < 4; ++i)
#pragma unroll
            for (int j = 0; j < 4; ++j) acc[i][j] = 0.f;
        for (int kk = 0; kk < DK; ++kk) {
            const float4 a = *(const float4*)&Qs[kk * SP + tr];
            const float4 c = *(const float4*)&Ks[kk * SP + tc];
            const float av[4] = {a.x, a.y, a.z, a.w};
            const float cv[4] = {c.x, c.y, c.z, c.w};
#pragma unroll
            for (int i = 0; i < 4; ++i)
#pragma unroll
                for (int j = 0; j < 4; ++j)
                    acc[i][j] = fmaf(av[i], cv[j], acc[i][j]);
        }
#pragma unroll
        for (int j = 0; j < 4; ++j) {
            const int c = tc + j;
            float4 o;
            o.x = acc[0][j] * 0.125f + ((tr + 0 < S && c < S) ? bi[(tr + 0) * S + c] : 0.f);
            o.y = acc[1][j] * 0.125f + ((tr + 1 < S && c < S) ? bi[(tr + 1) * S + c] : 0.f);
            o.z = acc[2][j] * 0.125f + ((tr + 2 < S && c < S) ? bi[(tr + 2) * S + c] : 0.f);
            o.w = acc[3][j] * 0.125f + ((tr + 3 < S && c < S) ? bi[(tr + 3) * S + c] : 0.f);
            *(float4*)&Ss[c * SP + tr] = o;
        }
    }
    __syncthreads();

    for (int i = tid; i < S * DK; i += 256) Qs[i] = vg[i];
    if (tid < S) {
        const int r = tid;
        float m = -1e30f;
        for (int c = 0; c < S; ++c) m = fmaxf(m, Ss[c * SP + r]);
        float sum = 0.f;
        for (int c = 0; c < S; ++c) {
            const float e = __expf(Ss[c * SP + r] - m);
            Ss[c * SP + r] = e;
            sum += e;
        }
        const float inv = 1.f / sum;
        for (int c = 0; c < S; ++c) Ss[c * SP + r] *= inv;
    }
    __syncthreads();

    for (int t = tid; t < 320; t += 256) {
        const int tr = (t >> 4) * 4;
        const int tc = (t & 15) * 4;
        float acc[4][4];
#pragma unroll
        for (int i = 0; i < 4; ++i)
#pragma unroll
            for (int j = 0; j < 4; ++j) acc[i][j] = 0.f;
        for (int c = 0; c < S; ++c) {
            const float4 p = *(const float4*)&Ss[c * SP + tr];
            const float4 vv = *(const float4*)&Qs[c * DK + tc];
            const float pv[4] = {p.x, p.y, p.z, p.w};
            const float vj[4] = {vv.x, vv.y, vv.z, vv.w};
#pragma unroll
            for (int i = 0; i < 4; ++i)
#pragma unroll
                for (int j = 0; j < 4; ++j)
                    acc[i][j] = fmaf(pv[i], vj[j], acc[i][j]);
        }
#pragma unroll
        for (int i = 0; i < 4; ++i) {
            const int r = tr + i;
            if (r < S) {
                float4 o = {acc[i][0], acc[i][1], acc[i][2], acc[i][3]};
                *(float4*)&ctx[((size_t)(b * S + r) * TD) + h * DK + tc] = o;
            }
        }
    }
}

// ---------------------------------------------------------------------------
// Region map (split path), peak ws use = 3*U*4 + 16MB = 506.7 MB  (< 654 MB
// proven available in round 2 by the fp32 path passing):
//   R1 = ws + 0     : q/k/v hi-lo planes (sequential reuse) -> ctx fp32
//   R2 = ws + U*4   : Q fp32 [B,H,S,DK]  -> ctx hi/lo planes
//   R3 = ws + 2U*4  : K fp32 [B,H,S,DK]
//   wp = ws + 3U*4  : 8 weight planes (16 MB)
//   V fp32 scratch lives in d_out (overwritten by final GEMM-O).
// ---------------------------------------------------------------------------
extern "C" void kernel_launch(void* const* d_in, const int* in_sizes, int n_in,
                              void* d_out, int out_size, void* d_ws, size_t ws_size,
                              hipStream_t stream)
{
    const float* query = (const float*)d_in[0];
    const float* key   = (const float*)d_in[1];
    const float* value = (const float*)d_in[2];
    // d_in[3] = token_coords (int64) — unused by the reference
    const float* Wq = (const float*)d_in[4];
    const float* Wk = (const float*)d_in[5];
    const float* Wv = (const float*)d_in[6];
    const float* Wo = (const float*)d_in[7];
    const float* rb = (const float*)d_in[8];
    float* out = (float*)d_out;

    const size_t U  = (size_t)TM * TD;         // 40,894,464 elems
    const size_t UW = (size_t)TD * TD;         // 1,048,576 elems
    const size_t SPLIT_BYTES = 3 * U * 4 + 8 * UW * 2;   // ~506.7 MB

    char* ws = (char*)d_ws;

    if (ws_size >= SPLIT_BYTES) {
        // ------- split-precision MFMA path -------
        _Float16* ah = (_Float16*)ws;                 // R1 as planes
        _Float16* al = ah + U;
        float*    cw = (float*)ws;                    // R1 as ctx fp32 (after GEMMs)
        float*    qw = (float*)(ws + 1 * U * 4);      // R2 as Q fp32
        _Float16* ch = (_Float16*)(ws + 1 * U * 4);   // R2 as ctx planes (after attn)
        _Float16* cl = ch + U;
        float*    kw = (float*)(ws + 2 * U * 4);      // R3: K fp32
        float*    vw = out;                           // d_out: V fp32 scratch
        _Float16* wp = (_Float16*)(ws + 3 * U * 4);   // 8 weight planes
        _Float16 *wqh = wp,          *wql = wp + UW;
        _Float16 *wkh = wp + 2 * UW, *wkl = wp + 3 * UW;
        _Float16 *wvh = wp + 4 * UW, *wvl = wp + 5 * UW;
        _Float16 *woh = wp + 6 * UW, *wol = wp + 7 * UW;

        const int n8a = (int)(U / 8);    // 5,111,808
        const int n8w = (int)(UW / 8);   // 131,072
        const int nwg = (TM / 128) * (TD / 128);   // 2496

        cvt_split<<<512, 256, 0, stream>>>(Wq, wqh, wql, n8w);
        cvt_split<<<512, 256, 0, stream>>>(Wk, wkh, wkl, n8w);
        cvt_split<<<512, 256, 0, stream>>>(Wv, wvh, wvl, n8w);
        cvt_split<<<512, 256, 0, stream>>>(Wo, woh, wol, n8w);

        cvt_split<<<2048, 256, 0, stream>>>(query, ah, al, n8a);
        gemm_split<1><<<nwg, 256, 0, stream>>>(ah, al, wqh, wql, qw);
        cvt_split<<<2048, 256, 0, stream>>>(key, ah, al, n8a);
        gemm_split<1><<<nwg, 256, 0, stream>>>(ah, al, wkh, wkl, kw);
        cvt_split<<<2048, 256, 0, stream>>>(value, ah, al, n8a);
        gemm_split<1><<<nwg, 256, 0, stream>>>(ah, al, wvh, wvl, vw);

        attn_kernel<<<TB * TH, 256, 0, stream>>>(qw, kw, vw, rb, cw);

        cvt_split<<<2048, 256, 0, stream>>>(cw, ch, cl, n8a);
        gemm_split<0><<<nwg, 256, 0, stream>>>(ch, cl, woh, wol, out);
    } else {
        // ------- fp32 vector fallback (requires 654 MB; insurance only) -------
        float* qw = (float*)ws;
        float* kw = qw + U;
        float* vw = kw + U;
        float* cw = vw + U;
        dim3 grid(TD / 128, TM / 128);
        gemm_nt_kernel<1><<<grid, 256, 0, stream>>>(query, Wq, qw);
        gemm_nt_kernel<1><<<grid, 256, 0, stream>>>(key,   Wk, kw);
        gemm_nt_kernel<1><<<grid, 256, 0, stream>>>(value, Wv, vw);
        attn_kernel<<<TB * TH, 256, 0, stream>>>(qw, kw, vw, rb, cw);
        gemm_nt_kernel<0><<<grid, 256, 0, stream>>>(cw, Wo, out);
    }
}